// Round 1
// baseline (67.919 us; speedup 1.0000x reference)
//
#include <hip/hip_runtime.h>

#define NPRE 32768
#define NPOST 32768
#define RR 64
#define BATCH 512
#define KSPLIT 64
#define KCHUNK 512  // NPRE / KSPLIT

typedef float f32x4 __attribute__((ext_vector_type(4)));
typedef __bf16 bf16x8 __attribute__((ext_vector_type(8)));
typedef unsigned short u16;
typedef unsigned int u32;

static __device__ __forceinline__ u16 f2bfu(float f) {
  u32 u = __builtin_bit_cast(u32, f);
  return (u16)((u + 0x7fffu + ((u >> 16) & 1u)) >> 16);  // RNE round to bf16
}
static __device__ __forceinline__ __bf16 u2bf(u16 s) {
  return __builtin_bit_cast(__bf16, s);
}

// ---- prep: U f32 [NPOST][RR] -> bf16 same layout --------------------------
__global__ __launch_bounds__(256) void k_prep_u(const float* __restrict__ U,
                                                u16* __restrict__ Ub) {
  int i = (blockIdx.x * 256 + threadIdx.x) * 4;
  float4 v = *reinterpret_cast<const float4*>(U + i);
  ushort4 o;
  o.x = f2bfu(v.x); o.y = f2bfu(v.y); o.z = f2bfu(v.z); o.w = f2bfu(v.w);
  *reinterpret_cast<ushort4*>(Ub + i) = o;
}

// ---- prep: V f32 [NPRE][RR] -> Vt bf16 [RR][NPRE] (transposed) ------------
__global__ __launch_bounds__(256) void k_prep_v(const float* __restrict__ V,
                                                u16* __restrict__ Vt) {
  int k0 = blockIdx.x * 64 + (threadIdx.x >> 6) * 16;  // 16 k's per thread
  int r = threadIdx.x & 63;                            // lane -> r (coalesced reads)
  u32 pk[8];
#pragma unroll
  for (int j = 0; j < 8; ++j) {
    u16 a = f2bfu(V[(size_t)(k0 + 2 * j) * RR + r]);
    u16 b = f2bfu(V[(size_t)(k0 + 2 * j + 1) * RR + r]);
    pk[j] = (u32)a | ((u32)b << 16);
  }
  u16* dst = Vt + (size_t)r * NPRE + k0;  // 32 B contiguous per thread
  *reinterpret_cast<uint4*>(dst) = make_uint4(pk[0], pk[1], pk[2], pk[3]);
  *reinterpret_cast<uint4*>(dst + 8) = make_uint4(pk[4], pk[5], pk[6], pk[7]);
}

// ---- GEMM1: zp[kc][b][r] partial = S[b][kchunk] @ V[kchunk][r] ------------
// wave tile: 16 b-rows x 64 r, K-chunk 512. No LDS: A (spikes f32) as 2x
// float4/lane + inline cvt; B direct bf16x8 from Vt. 32 Mtiles x 64 kchunks.
__global__ __launch_bounds__(256) void k1(const float* __restrict__ S,
                                          const u16* __restrict__ Vt,
                                          float* __restrict__ zp) {
  int bid = blockIdx.x;
  int eff = (bid & 7) * 64 + (bid >> 3);  // bijective XCD swizzle (512 % 8 == 0)
  int grp = eff & 7;
  int kc = eff >> 3;                       // per-XCD contiguous kc -> V slice in L2
  int lane = threadIdx.x & 63;
  int w = threadIdx.x >> 6;
  int mt = grp * 4 + w;                    // 0..31
  int l15 = lane & 15, g = lane >> 4;
  const float* A = S + (size_t)(mt * 16 + l15) * NPRE + kc * KCHUNK + g * 8;
  const u16* B = Vt + (size_t)l15 * NPRE + kc * KCHUNK + g * 8;
  f32x4 acc[4] = {};
#pragma unroll 4
  for (int ks = 0; ks < KCHUNK / 32; ++ks) {
    int ko = ks * 32;
    float4 a0 = *reinterpret_cast<const float4*>(A + ko);
    float4 a1 = *reinterpret_cast<const float4*>(A + ko + 4);
    bf16x8 af;
    af[0] = u2bf(f2bfu(a0.x)); af[1] = u2bf(f2bfu(a0.y));
    af[2] = u2bf(f2bfu(a0.z)); af[3] = u2bf(f2bfu(a0.w));
    af[4] = u2bf(f2bfu(a1.x)); af[5] = u2bf(f2bfu(a1.y));
    af[6] = u2bf(f2bfu(a1.z)); af[7] = u2bf(f2bfu(a1.w));
    bf16x8 b0 = *reinterpret_cast<const bf16x8*>(B + ko);
    bf16x8 b1 = *reinterpret_cast<const bf16x8*>(B + 16 * NPRE + ko);
    bf16x8 b2 = *reinterpret_cast<const bf16x8*>(B + 32 * NPRE + ko);
    bf16x8 b3 = *reinterpret_cast<const bf16x8*>(B + 48 * NPRE + ko);
    acc[0] = __builtin_amdgcn_mfma_f32_16x16x32_bf16(af, b0, acc[0], 0, 0, 0);
    acc[1] = __builtin_amdgcn_mfma_f32_16x16x32_bf16(af, b1, acc[1], 0, 0, 0);
    acc[2] = __builtin_amdgcn_mfma_f32_16x16x32_bf16(af, b2, acc[2], 0, 0, 0);
    acc[3] = __builtin_amdgcn_mfma_f32_16x16x32_bf16(af, b3, acc[3], 0, 0, 0);
  }
  // D layout (verified): col = lane&15, row = (lane>>4)*4 + reg
  float* out = zp + ((size_t)kc * BATCH + mt * 16) * RR;
#pragma unroll
  for (int t = 0; t < 4; ++t)
#pragma unroll
    for (int q = 0; q < 4; ++q)
      out[(g * 4 + q) * RR + t * 16 + l15] = acc[t][q];
}

// ---- reduce split-K partials -> z bf16 [BATCH][RR] ------------------------
__global__ __launch_bounds__(256) void k_red(const float* __restrict__ zp,
                                             u16* __restrict__ zb) {
  int i = blockIdx.x * 256 + threadIdx.x;
  float s0 = 0.f, s1 = 0.f, s2 = 0.f, s3 = 0.f;
#pragma unroll
  for (int t = 0; t < KSPLIT; t += 4) {
    s0 += zp[(size_t)t * (BATCH * RR) + i];
    s1 += zp[(size_t)(t + 1) * (BATCH * RR) + i];
    s2 += zp[(size_t)(t + 2) * (BATCH * RR) + i];
    s3 += zp[(size_t)(t + 3) * (BATCH * RR) + i];
  }
  zb[i] = f2bfu((s0 + s1) + (s2 + s3));
}

// ---- GEMM2: y[b][n] = z[b][:] @ U[n][:]  (K = RR = 64) --------------------
// wave tile: 16 b x 64 n. A = z rows (bf16, L2-hot), B = U rows (native
// layout, bf16). No LDS. 4096 blocks, XCD swizzle gives each XCD a
// contiguous n-range (512 KB U slice resident in its L2).
__global__ __launch_bounds__(256) void k2(const u16* __restrict__ zb,
                                          const u16* __restrict__ Ub,
                                          float* __restrict__ y) {
  int bid = blockIdx.x;
  int eff = (bid & 7) * 512 + (bid >> 3);  // bijective (4096 % 8 == 0)
  int bt = eff & 7;
  int nt = eff >> 3;
  int lane = threadIdx.x & 63;
  int w = threadIdx.x >> 6;
  int l15 = lane & 15, g = lane >> 4;
  int b0 = bt * 64 + w * 16;
  int n0 = nt * 64;
  const u16* A = zb + (b0 + l15) * RR + g * 8;
  const u16* B = Ub + (size_t)(n0 + l15) * RR + g * 8;
  f32x4 acc[4] = {};
#pragma unroll
  for (int ks = 0; ks < 2; ++ks) {
    int ko = ks * 32;
    bf16x8 a = *reinterpret_cast<const bf16x8*>(A + ko);
#pragma unroll
    for (int t = 0; t < 4; ++t) {
      bf16x8 b = *reinterpret_cast<const bf16x8*>(B + t * (16 * RR) + ko);
      acc[t] = __builtin_amdgcn_mfma_f32_16x16x32_bf16(a, b, acc[t], 0, 0, 0);
    }
  }
  float* out = y + (size_t)b0 * NPOST + n0;
#pragma unroll
  for (int t = 0; t < 4; ++t)
#pragma unroll
    for (int q = 0; q < 4; ++q)
      out[(size_t)(g * 4 + q) * NPOST + t * 16 + l15] = acc[t][q];
}

extern "C" void kernel_launch(void* const* d_in, const int* in_sizes, int n_in,
                              void* d_out, int out_size, void* d_ws, size_t ws_size,
                              hipStream_t stream) {
  const float* spikes = (const float*)d_in[0];
  const float* U = (const float*)d_in[1];
  const float* V = (const float*)d_in[2];
  // d_in[3..5]: CSR mask — dead in the reference, unused.
  float* y = (float*)d_out;
  char* ws = (char*)d_ws;
  u16* Vt = (u16*)ws;                        // 4 MiB  [RR][NPRE] bf16
  u16* Ub = (u16*)(ws + (4u << 20));         // 4 MiB  [NPOST][RR] bf16
  float* zp = (float*)(ws + (8u << 20));     // 8 MiB  [KSPLIT][BATCH][RR] f32
  u16* zb = (u16*)(ws + (16u << 20));        // 64 KiB [BATCH][RR] bf16

  k_prep_v<<<NPRE / 64, 256, 0, stream>>>(V, Vt);
  k_prep_u<<<(NPOST * RR) / (4 * 256), 256, 0, stream>>>(U, Ub);
  k1<<<512, 256, 0, stream>>>(spikes, Vt, zp);
  k_red<<<(BATCH * RR) / 256, 256, 0, stream>>>(zp, zb);
  k2<<<4096, 256, 0, stream>>>(zb, Ub, y);
}